// Round 12
// baseline (116.843 us; speedup 1.0000x reference)
//
#include <hip/hip_runtime.h>
#include <hip/hip_fp16.h>

#define NN 50000
#define NE 800000
#define IN_DIM 128
#define OUT_DIM 64
#define NEG 0.2f

#define BSHIFT 7
#define BNODES 128              // nodes per bucket
#define NBUCK 391               // ceil(50000 / 128)
#define HALFCAP 2560            // window per bucket: mean 2048, +11 sigma
#define CHUNK 4096              // edges per bin block
#define BIN_BLOCKS 196          // ceil(NE / CHUNK)
#define GEMM_BLOCKS 391         // ceil(NN / 128)

#define XS_STRIDE 136           // bf16 elems/row: 272 B, 16B-aligned

typedef short short8 __attribute__((ext_vector_type(8)));
typedef float f32x4 __attribute__((ext_vector_type(4)));

__device__ __forceinline__ unsigned short f2bf(float f) {
    unsigned u = __float_as_uint(f);
    u += 0x7FFFu + ((u >> 16) & 1u);
    return (unsigned short)(u >> 16);
}

// ---- Kernel 0: zero the bucket cursors (pure-kernel graph) -----------------
// NOTE: hipMemsetAsync variant measured +4us WORSE (r6/r7). Keep this kernel.
__global__ __launch_bounds__(512) void gat_zero(int* __restrict__ bucket_cur) {
    if (threadIdx.x < NBUCK) bucket_cur[threadIdx.x] = 0;
}

// ---- Kernel A (512 threads): fused [edge bin-sort] (blocks 0..195, first)
//      and [h2 = fp16(x@W) via bf16 MFMA, 128-row tiles] --------------------
__global__ __launch_bounds__(512) void gat_gemm_bin(
    const float* __restrict__ x, const float* __restrict__ W,
    const float* __restrict__ att_src, const float* __restrict__ att_dst,
    const int* __restrict__ src, const int* __restrict__ dst,
    unsigned short* __restrict__ h2, float* __restrict__ a_src,
    float* __restrict__ a_dst,
    int* __restrict__ gbucket, int* __restrict__ bucket_cur)
{
    __shared__ __align__(16) unsigned short xs[128 * XS_STRIDE]; // 34816 B
    __shared__ __align__(16) unsigned short wt[64 * XS_STRIDE];  // 17408 B
    const int tid = threadIdx.x;
    const int lane = tid & 63, wid = tid >> 6;

    if (blockIdx.x < BIN_BLOCKS) {
        // ---------------- bin sort, single global pass ----------------
        // record = {bkt:9 | src:16 | dlow:7}
        int* recs_in  = (int*)xs;            // [CHUNK] 16 KB
        int* bcnt     = recs_in + CHUNK;     // [512]
        int* cur      = bcnt + 512;          // [512]
        int* lbase    = cur + 512;           // [512]
        int* comb     = lbase + 512;         // [512]
        int* wsum     = comb + 512;          // [8]
        int* recs_out = (int*)wt;            // [CHUNK] 16 KB
        const int e0 = blockIdx.x * CHUNK;
        const int total = (e0 + CHUNK < NE ? CHUNK : NE - e0);

        bcnt[tid] = 0;
        __syncthreads();
#pragma unroll
        for (int k = 0; k < CHUNK / 512; ++k) {
            const int e = e0 + k * 512 + tid;
            if (e < NE) {
                const int d = dst[e];
                const int bkt = d >> BSHIFT;
                recs_in[k * 512 + tid] =
                    (bkt << 23) | (src[e] << BSHIFT) | (d & (BNODES - 1));
                atomicAdd(&bcnt[bkt], 1);
            }
        }
        __syncthreads();
        // wave-shuffle scan of bcnt (512 entries, 8 waves, 2 barriers)
        const int v = bcnt[tid];
        int incl = v;
#pragma unroll
        for (int off = 1; off < 64; off <<= 1) {
            const int n = __shfl_up(incl, off, 64);
            if (lane >= off) incl += n;
        }
        if (lane == 63) wsum[wid] = incl;
        __syncthreads();
        int wpre = 0;
#pragma unroll
        for (int w = 0; w < 8; ++w)
            if (w < wid) wpre += wsum[w];
        const int excl = wpre + incl - v;
        lbase[tid] = excl; cur[tid] = excl;
        int gb = 0;
        if (tid < NBUCK && v) gb = atomicAdd(&bucket_cur[tid], v);
        comb[tid] = gb - excl;
        __syncthreads();
        // place (LDS -> LDS, grouped by bucket)
#pragma unroll
        for (int k = 0; k < CHUNK / 512; ++k) {
            const int idx = k * 512 + tid;
            if (idx < total) {
                const int r = recs_in[idx];
                const unsigned bkt = (unsigned)r >> 23;
                const int pos = atomicAdd(&cur[bkt], 1);
                recs_out[pos] = r;
            }
        }
        __syncthreads();
        // coalesced flush
        for (int j = tid; j < total; j += 512) {
            const int r = recs_out[j];
            const unsigned bkt = (unsigned)r >> 23;
            const int rel = comb[bkt] + j;
            if (rel < HALFCAP)
                gbucket[bkt * HALFCAP + rel] = r & 0x7FFFFF;
        }
        return;
    }

    // ---------------- GEMM path: bf16 MFMA, 128x64 tile, 8 waves -------
    const int block_row = (blockIdx.x - BIN_BLOCKS) * 128;

    for (int t = tid; t < 128 * 32; t += 512) {
        const int r = t >> 5, k = (t & 31) << 2;
        const int row = block_row + r;
        float4 v = make_float4(0.f, 0.f, 0.f, 0.f);
        if (row < NN) v = *(const float4*)(x + (size_t)row * IN_DIM + k);
        ushort4 p;
        p.x = f2bf(v.x); p.y = f2bf(v.y); p.z = f2bf(v.z); p.w = f2bf(v.w);
        *(ushort4*)&xs[r * XS_STRIDE + k] = p;
    }
    for (int t = tid; t < 128 * 16; t += 512) {
        const int k = t >> 4, n4 = (t & 15) << 2;
        const float4 v = *(const float4*)(W + k * 64 + n4);
        wt[(n4 + 0) * XS_STRIDE + k] = f2bf(v.x);
        wt[(n4 + 1) * XS_STRIDE + k] = f2bf(v.y);
        wt[(n4 + 2) * XS_STRIDE + k] = f2bf(v.z);
        wt[(n4 + 3) * XS_STRIDE + k] = f2bf(v.w);
    }
    __syncthreads();

    const int m = lane & 15, quad = lane >> 4;

    f32x4 acc[4];
#pragma unroll
    for (int ct = 0; ct < 4; ++ct) acc[ct] = (f32x4){0.f, 0.f, 0.f, 0.f};

    const unsigned short* xrow = &xs[(wid * 16 + m) * XS_STRIDE + quad * 8];
#pragma unroll
    for (int kt = 0; kt < 4; ++kt) {
        short8 af = *(const short8*)(xrow + kt * 32);
#pragma unroll
        for (int ct = 0; ct < 4; ++ct) {
            short8 bf = *(const short8*)(&wt[(ct * 16 + m) * XS_STRIDE + kt * 32 + quad * 8]);
            acc[ct] = __builtin_amdgcn_mfma_f32_16x16x32_bf16(af, bf, acc[ct], 0, 0, 0);
        }
    }

    float as_c[4], ad_c[4];
#pragma unroll
    for (int ct = 0; ct < 4; ++ct) {
        as_c[ct] = att_src[ct * 16 + m];
        ad_c[ct] = att_dst[ct * 16 + m];
    }
    float ps[4], pd[4];
#pragma unroll
    for (int reg = 0; reg < 4; ++reg) {
        float s = 0.f, d = 0.f;
#pragma unroll
        for (int ct = 0; ct < 4; ++ct) {
            s += acc[ct][reg] * as_c[ct];
            d += acc[ct][reg] * ad_c[ct];
        }
        ps[reg] = s; pd[reg] = d;
    }
#pragma unroll
    for (int off = 1; off < 16; off <<= 1) {
#pragma unroll
        for (int reg = 0; reg < 4; ++reg) {
            ps[reg] += __shfl_xor(ps[reg], off, 64);
            pd[reg] += __shfl_xor(pd[reg], off, 64);
        }
    }
    if (m == 0) {
#pragma unroll
        for (int reg = 0; reg < 4; ++reg) {
            const int row = block_row + wid * 16 + quad * 4 + reg;
            if (row < NN) { a_src[row] = ps[reg]; a_dst[row] = pd[reg]; }
        }
    }

    __syncthreads();
    unsigned short* hs = xs;               // 128 rows x stride 72
#pragma unroll
    for (int ct = 0; ct < 4; ++ct)
#pragma unroll
        for (int reg = 0; reg < 4; ++reg)
            hs[(wid * 16 + quad * 4 + reg) * 72 + ct * 16 + m] =
                __half_as_ushort(__float2half(acc[ct][reg]));
    __syncthreads();
    {
        const int r = tid >> 2, c = (tid & 3) * 16;
        const int row = block_row + r;
        if (row < NN) {
            uint4 v0 = *(const uint4*)&hs[r * 72 + c];
            uint4 v1 = *(const uint4*)&hs[r * 72 + c + 8];
            *(uint4*)(h2 + (size_t)row * 64 + c) = v0;
            *(uint4*)(h2 + (size_t)row * 64 + c + 8) = v1;
        }
    }
}

// ---- Kernel B: FUSED per-bucket counting sort (LDS) + exp + aggregation ----
// 391 blocks (one per 128-node bucket), 1024 threads.
// Phase 4: 16 lanes/node x 4 columns, TWO passes over the 128 nodes.
// Rationale (r9/r11 post-mortems): B sits just above the 64-VGPR step ->
// 1 block/CU, 1.53 dispatch rounds (24% tail) and halved MLP. Forcing
// <=64 via launch_bounds spilled (+2.4us). This halves phase-4 live state
// (acc 8->4, uint4->uint2 pipeline) to get under 64 VGPR STRUCTURALLY.
// Per-column accumulation sequence unchanged -> bit-identical numerics.
__global__ __launch_bounds__(1024) void gat_sortagg(
    const int* __restrict__ gbucket, const int* __restrict__ bucket_cur,
    const __half* __restrict__ h2, const float* __restrict__ a_src,
    const float* __restrict__ a_dst, const float* __restrict__ bias,
    float* __restrict__ out)
{
    __shared__ int raw[HALFCAP];                 // 10.2 KB
    __shared__ unsigned srtex[HALFCAP];          // 10.2 KB packed {ex, src}
    __shared__ int hist[BNODES];
    __shared__ int scanb[BNODES];
    __shared__ int cur[BNODES];
    __shared__ float ads[BNODES];
    __shared__ float ass[BNODES];                // own-node a_src cache
    __shared__ int wsum[2];
    const int b = blockIdx.x;
    const int tid = threadIdx.x;
    const int node0 = b << BSHIFT;

    int cnt_b = bucket_cur[b];
    if (cnt_b > HALFCAP) cnt_b = HALFCAP;
    const int* win = gbucket + (size_t)b * HALFCAP;

    if (tid < BNODES) {
        hist[tid] = 0;
        const int n = node0 + tid;
        ads[tid] = (n < NN) ? a_dst[n] : 0.f;
        ass[tid] = (n < NN) ? a_src[n] : 0.f;
    }
    __syncthreads();
    for (int i = tid; i < cnt_b; i += 1024) {
        const int r = win[i];
        raw[i] = r;
        atomicAdd(&hist[r & (BNODES - 1)], 1);
    }
    __syncthreads();
    // wave-shuffle scan of hist (128 entries, 2 waves, 2 barriers)
    const int lane = tid & 63;
    int v = 0, incl = 0;
    if (tid < BNODES) {
        v = hist[tid];
        incl = v;
#pragma unroll
        for (int off = 1; off < 64; off <<= 1) {
            const int n = __shfl_up(incl, off, 64);
            if (lane >= off) incl += n;
        }
        if (lane == 63) wsum[tid >> 6] = incl;
    }
    __syncthreads();
    if (tid < BNODES) {
        const int inclT = incl + ((tid >= 64) ? wsum[0] : 0);
        scanb[tid] = inclT;
        cur[tid] = inclT - v;
    }
    __syncthreads();
    for (int i = tid; i < cnt_b; i += 1024) {
        const int r = raw[i];
        const int dl = r & (BNODES - 1);
        const int s = (r >> BSHIFT) & 0xFFFF;
        float ev = a_src[s] + ads[dl];
        ev = ev > 0.f ? ev : NEG * ev;
        const float ex = __expf(ev);
        const int pos = atomicAdd(&cur[dl], 1);
        srtex[pos] = (unsigned)s |
                     ((unsigned)__half_as_ushort(__float2half(ex)) << 16);
    }
    __syncthreads();

    // ---------------- phase 4: 16 lanes/node, 4 columns/lane, 2 passes -----
    {
        const int g  = tid >> 4;        // node slot within pass: 0..63
        const int cq = tid & 15;        // 8B column slice (4 floats out)
#pragma unroll
        for (int k = 0; k < 2; ++k) {
            const int ln = k * 64 + g;
            const int node = node0 + ln;
            if (node < NN) {
                const int deg = hist[ln];
                const int rbase = scanb[ln] - deg;

                // self logit from LDS
                float v2 = ass[ln] + ads[ln];
                v2 = v2 > 0.f ? v2 : NEG * v2;
                const float exs = __expf(v2);

                // self row: 8B/lane, 16 lanes = full 128B row
                uint2 hp = *(const uint2*)(h2 + ((size_t)node << 6) + (cq << 2));

                // 2-deep rolling prefetch over the node's edge list
                float eA = 0.f, eB = 0.f;
                uint2 gA = make_uint2(0, 0), gB = make_uint2(0, 0);
                if (0 < deg) {
                    const unsigned p = srtex[rbase];      // 16-lane broadcast
                    const int s = (int)(p & 0xffffu);
                    eA = __half2float(__ushort_as_half((unsigned short)(p >> 16)));
                    gA = *(const uint2*)(h2 + ((size_t)s << 6) + (cq << 2));
                }
                if (1 < deg) {
                    const unsigned p = srtex[rbase + 1];
                    const int s = (int)(p & 0xffffu);
                    eB = __half2float(__ushort_as_half((unsigned short)(p >> 16)));
                    gB = *(const uint2*)(h2 + ((size_t)s << 6) + (cq << 2));
                }

                float a0, a1, a2, a3;
                {
                    const __half2* hh = (const __half2*)&hp;
                    float2 f0 = __half22float2(hh[0]);
                    float2 f1 = __half22float2(hh[1]);
                    a0 = exs * f0.x; a1 = exs * f0.y;
                    a2 = exs * f1.x; a3 = exs * f1.y;
                }
                float den = exs;   // identical in all 16 lanes of the group

                for (int i = 0; i < deg; ++i) {
                    float eC = 0.f; uint2 gC = make_uint2(0, 0);
                    if (i + 2 < deg) {
                        const unsigned p = srtex[rbase + i + 2];
                        const int s = (int)(p & 0xffffu);
                        eC = __half2float(__ushort_as_half((unsigned short)(p >> 16)));
                        gC = *(const uint2*)(h2 + ((size_t)s << 6) + (cq << 2));
                    }
                    {
                        const __half2* gh = (const __half2*)&gA;
                        float2 f0 = __half22float2(gh[0]);
                        float2 f1 = __half22float2(gh[1]);
                        a0 += eA * f0.x; a1 += eA * f0.y;
                        a2 += eA * f1.x; a3 += eA * f1.y;
                        den += eA;
                    }
                    eA = eB; gA = gB;
                    eB = eC; gB = gC;
                }

                const float inv = 1.f / den;
                const float4 bb = *(const float4*)(bias + (cq << 2));
                float4 o;
                o.x = a0 * inv + bb.x; o.y = a1 * inv + bb.y;
                o.z = a2 * inv + bb.z; o.w = a3 * inv + bb.w;
                // 16 lanes x 16B = 256B contiguous per node
                *(float4*)(out + ((size_t)node << 6) + (cq << 2)) = o;
            }
        }
    }
}

extern "C" void kernel_launch(void* const* d_in, const int* in_sizes, int n_in,
                              void* d_out, int out_size, void* d_ws, size_t ws_size,
                              hipStream_t stream) {
    const float* x       = (const float*)d_in[0];
    const int*   eidx    = (const int*)d_in[1];   // [2, NE] row-major
    const float* W       = (const float*)d_in[2];
    const float* att_src = (const float*)d_in[3];
    const float* att_dst = (const float*)d_in[4];
    const float* bias    = (const float*)d_in[5];
    float* out = (float*)d_out;

    // ws: h2 [NN*64 fp16 = 6.4MB] | gbucket [391*2560*4 = 4.0MB]
    //   | a_src [NN] | a_dst [NN] | bucket_cur [NBUCK]
    unsigned short* h2 = (unsigned short*)d_ws;
    int*   gbucket = (int*)((char*)d_ws + (size_t)NN * OUT_DIM * 2);
    float* a_src   = (float*)(gbucket + (size_t)NBUCK * HALFCAP);
    float* a_dst   = a_src + NN;
    int*   bucket_cur = (int*)(a_dst + NN);

    const int* src = eidx;
    const int* dst = eidx + NE;

    gat_zero<<<1, 512, 0, stream>>>(bucket_cur);
    gat_gemm_bin<<<GEMM_BLOCKS + BIN_BLOCKS, 512, 0, stream>>>(
        x, W, att_src, att_dst, src, dst, h2, a_src, a_dst, gbucket, bucket_cur);
    gat_sortagg<<<NBUCK, 1024, 0, stream>>>(
        gbucket, bucket_cur, (const __half*)h2, a_src, a_dst, bias, out);
}

// Round 13
// 115.417 us; speedup vs baseline: 1.0124x; 1.0124x over previous
//
#include <hip/hip_runtime.h>
#include <hip/hip_fp16.h>

#define NN 50000
#define NE 800000
#define IN_DIM 128
#define OUT_DIM 64
#define NEG 0.2f

#define BSHIFT 7
#define BNODES 128              // nodes per bucket
#define NBUCK 391               // ceil(50000 / 128)
#define HALFCAP 2560            // window per bucket: mean 2048, +11 sigma
#define CHUNK 4096              // edges per bin block
#define BIN_BLOCKS 196          // ceil(NE / CHUNK)
#define GEMM_BLOCKS 391         // ceil(NN / 128)

#define XS_STRIDE 136           // bf16 elems/row: 272 B, 16B-aligned

typedef short short8 __attribute__((ext_vector_type(8)));
typedef float f32x4 __attribute__((ext_vector_type(4)));

__device__ __forceinline__ unsigned short f2bf(float f) {
    unsigned u = __float_as_uint(f);
    u += 0x7FFFu + ((u >> 16) & 1u);
    return (unsigned short)(u >> 16);
}

// ---- Kernel 0: zero the bucket cursors (pure-kernel graph) -----------------
// NOTE: hipMemsetAsync variant measured +4us WORSE (r6/r7). Keep this kernel.
__global__ __launch_bounds__(512) void gat_zero(int* __restrict__ bucket_cur) {
    if (threadIdx.x < NBUCK) bucket_cur[threadIdx.x] = 0;
}

// ---- Kernel A (512 threads): fused [edge bin-sort] (blocks 0..195, first)
//      and [h2 = fp16(x@W) via bf16 MFMA, 128-row tiles] --------------------
__global__ __launch_bounds__(512) void gat_gemm_bin(
    const float* __restrict__ x, const float* __restrict__ W,
    const float* __restrict__ att_src, const float* __restrict__ att_dst,
    const int* __restrict__ src, const int* __restrict__ dst,
    unsigned short* __restrict__ h2, float* __restrict__ a_src,
    float* __restrict__ a_dst,
    int* __restrict__ gbucket, int* __restrict__ bucket_cur)
{
    __shared__ __align__(16) unsigned short xs[128 * XS_STRIDE]; // 34816 B
    __shared__ __align__(16) unsigned short wt[64 * XS_STRIDE];  // 17408 B
    const int tid = threadIdx.x;
    const int lane = tid & 63, wid = tid >> 6;

    if (blockIdx.x < BIN_BLOCKS) {
        // ---------------- bin sort, single global pass ----------------
        // record = {bkt:9 | src:16 | dlow:7}
        int* recs_in  = (int*)xs;            // [CHUNK] 16 KB
        int* bcnt     = recs_in + CHUNK;     // [512]
        int* cur      = bcnt + 512;          // [512]
        int* lbase    = cur + 512;           // [512]
        int* comb     = lbase + 512;         // [512]
        int* wsum     = comb + 512;          // [8]
        int* recs_out = (int*)wt;            // [CHUNK] 16 KB
        const int e0 = blockIdx.x * CHUNK;
        const int total = (e0 + CHUNK < NE ? CHUNK : NE - e0);

        bcnt[tid] = 0;
        __syncthreads();
#pragma unroll
        for (int k = 0; k < CHUNK / 512; ++k) {
            const int e = e0 + k * 512 + tid;
            if (e < NE) {
                const int d = dst[e];
                const int bkt = d >> BSHIFT;
                recs_in[k * 512 + tid] =
                    (bkt << 23) | (src[e] << BSHIFT) | (d & (BNODES - 1));
                atomicAdd(&bcnt[bkt], 1);
            }
        }
        __syncthreads();
        // wave-shuffle scan of bcnt (512 entries, 8 waves, 2 barriers)
        const int v = bcnt[tid];
        int incl = v;
#pragma unroll
        for (int off = 1; off < 64; off <<= 1) {
            const int n = __shfl_up(incl, off, 64);
            if (lane >= off) incl += n;
        }
        if (lane == 63) wsum[wid] = incl;
        __syncthreads();
        int wpre = 0;
#pragma unroll
        for (int w = 0; w < 8; ++w)
            if (w < wid) wpre += wsum[w];
        const int excl = wpre + incl - v;
        lbase[tid] = excl; cur[tid] = excl;
        int gb = 0;
        if (tid < NBUCK && v) gb = atomicAdd(&bucket_cur[tid], v);
        comb[tid] = gb - excl;
        __syncthreads();
        // place (LDS -> LDS, grouped by bucket)
#pragma unroll
        for (int k = 0; k < CHUNK / 512; ++k) {
            const int idx = k * 512 + tid;
            if (idx < total) {
                const int r = recs_in[idx];
                const unsigned bkt = (unsigned)r >> 23;
                const int pos = atomicAdd(&cur[bkt], 1);
                recs_out[pos] = r;
            }
        }
        __syncthreads();
        // coalesced flush
        for (int j = tid; j < total; j += 512) {
            const int r = recs_out[j];
            const unsigned bkt = (unsigned)r >> 23;
            const int rel = comb[bkt] + j;
            if (rel < HALFCAP)
                gbucket[bkt * HALFCAP + rel] = r & 0x7FFFFF;
        }
        return;
    }

    // ---------------- GEMM path: bf16 MFMA, 128x64 tile, 8 waves -------
    const int block_row = (blockIdx.x - BIN_BLOCKS) * 128;

    for (int t = tid; t < 128 * 32; t += 512) {
        const int r = t >> 5, k = (t & 31) << 2;
        const int row = block_row + r;
        float4 v = make_float4(0.f, 0.f, 0.f, 0.f);
        if (row < NN) v = *(const float4*)(x + (size_t)row * IN_DIM + k);
        ushort4 p;
        p.x = f2bf(v.x); p.y = f2bf(v.y); p.z = f2bf(v.z); p.w = f2bf(v.w);
        *(ushort4*)&xs[r * XS_STRIDE + k] = p;
    }
    for (int t = tid; t < 128 * 16; t += 512) {
        const int k = t >> 4, n4 = (t & 15) << 2;
        const float4 v = *(const float4*)(W + k * 64 + n4);
        wt[(n4 + 0) * XS_STRIDE + k] = f2bf(v.x);
        wt[(n4 + 1) * XS_STRIDE + k] = f2bf(v.y);
        wt[(n4 + 2) * XS_STRIDE + k] = f2bf(v.z);
        wt[(n4 + 3) * XS_STRIDE + k] = f2bf(v.w);
    }
    __syncthreads();

    const int m = lane & 15, quad = lane >> 4;

    f32x4 acc[4];
#pragma unroll
    for (int ct = 0; ct < 4; ++ct) acc[ct] = (f32x4){0.f, 0.f, 0.f, 0.f};

    const unsigned short* xrow = &xs[(wid * 16 + m) * XS_STRIDE + quad * 8];
#pragma unroll
    for (int kt = 0; kt < 4; ++kt) {
        short8 af = *(const short8*)(xrow + kt * 32);
#pragma unroll
        for (int ct = 0; ct < 4; ++ct) {
            short8 bf = *(const short8*)(&wt[(ct * 16 + m) * XS_STRIDE + kt * 32 + quad * 8]);
            acc[ct] = __builtin_amdgcn_mfma_f32_16x16x32_bf16(af, bf, acc[ct], 0, 0, 0);
        }
    }

    float as_c[4], ad_c[4];
#pragma unroll
    for (int ct = 0; ct < 4; ++ct) {
        as_c[ct] = att_src[ct * 16 + m];
        ad_c[ct] = att_dst[ct * 16 + m];
    }
    float ps[4], pd[4];
#pragma unroll
    for (int reg = 0; reg < 4; ++reg) {
        float s = 0.f, d = 0.f;
#pragma unroll
        for (int ct = 0; ct < 4; ++ct) {
            s += acc[ct][reg] * as_c[ct];
            d += acc[ct][reg] * ad_c[ct];
        }
        ps[reg] = s; pd[reg] = d;
    }
#pragma unroll
    for (int off = 1; off < 16; off <<= 1) {
#pragma unroll
        for (int reg = 0; reg < 4; ++reg) {
            ps[reg] += __shfl_xor(ps[reg], off, 64);
            pd[reg] += __shfl_xor(pd[reg], off, 64);
        }
    }
    if (m == 0) {
#pragma unroll
        for (int reg = 0; reg < 4; ++reg) {
            const int row = block_row + wid * 16 + quad * 4 + reg;
            if (row < NN) { a_src[row] = ps[reg]; a_dst[row] = pd[reg]; }
        }
    }

    __syncthreads();
    unsigned short* hs = xs;               // 128 rows x stride 72
#pragma unroll
    for (int ct = 0; ct < 4; ++ct)
#pragma unroll
        for (int reg = 0; reg < 4; ++reg)
            hs[(wid * 16 + quad * 4 + reg) * 72 + ct * 16 + m] =
                __half_as_ushort(__float2half(acc[ct][reg]));
    __syncthreads();
    {
        const int r = tid >> 2, c = (tid & 3) * 16;
        const int row = block_row + r;
        if (row < NN) {
            uint4 v0 = *(const uint4*)&hs[r * 72 + c];
            uint4 v1 = *(const uint4*)&hs[r * 72 + c + 8];
            *(uint4*)(h2 + (size_t)row * 64 + c) = v0;
            *(uint4*)(h2 + (size_t)row * 64 + c + 8) = v1;
        }
    }
}

// ---- Kernel B: FUSED per-bucket counting sort (LDS) + exp + aggregation ----
// 391 blocks (one per 128-node bucket), 512 threads (8 waves).
// R12 change: block 1024 -> 512. B is >64 VGPR (r11 spill test), so a
// 1024-thr block (16 waves) = 1 block/CU -> 1.53 dispatch rounds + no
// cross-block latency overlap. At 512 thr, 2 blocks co-reside per CU
// (same 16 waves) -> all 391 blocks resident, barriers/gathers of the
// two blocks overlap. Phase-4 inner body is BIT-IDENTICAL to the 113.1
// anchor (8 lanes/node, uint4, acc[8], 2-deep pipeline), two passes.
__global__ __launch_bounds__(512) void gat_sortagg(
    const int* __restrict__ gbucket, const int* __restrict__ bucket_cur,
    const __half* __restrict__ h2, const float* __restrict__ a_src,
    const float* __restrict__ a_dst, const float* __restrict__ bias,
    float* __restrict__ out)
{
    __shared__ int raw[HALFCAP];                 // 10.2 KB
    __shared__ unsigned srtex[HALFCAP];          // 10.2 KB packed {ex, src}
    __shared__ int hist[BNODES];
    __shared__ int scanb[BNODES];
    __shared__ int cur[BNODES];
    __shared__ float ads[BNODES];
    __shared__ float ass[BNODES];                // own-node a_src cache
    __shared__ int wsum[2];
    const int b = blockIdx.x;
    const int tid = threadIdx.x;
    const int node0 = b << BSHIFT;

    int cnt_b = bucket_cur[b];
    if (cnt_b > HALFCAP) cnt_b = HALFCAP;
    const int* win = gbucket + (size_t)b * HALFCAP;

    if (tid < BNODES) {
        hist[tid] = 0;
        const int n = node0 + tid;
        ads[tid] = (n < NN) ? a_dst[n] : 0.f;
        ass[tid] = (n < NN) ? a_src[n] : 0.f;
    }
    __syncthreads();
    for (int i = tid; i < cnt_b; i += 512) {
        const int r = win[i];
        raw[i] = r;
        atomicAdd(&hist[r & (BNODES - 1)], 1);
    }
    __syncthreads();
    // wave-shuffle scan of hist (128 entries, 2 waves, 2 barriers)
    const int lane = tid & 63;
    int v = 0, incl = 0;
    if (tid < BNODES) {
        v = hist[tid];
        incl = v;
#pragma unroll
        for (int off = 1; off < 64; off <<= 1) {
            const int n = __shfl_up(incl, off, 64);
            if (lane >= off) incl += n;
        }
        if (lane == 63) wsum[tid >> 6] = incl;
    }
    __syncthreads();
    if (tid < BNODES) {
        const int inclT = incl + ((tid >= 64) ? wsum[0] : 0);
        scanb[tid] = inclT;
        cur[tid] = inclT - v;
    }
    __syncthreads();
    for (int i = tid; i < cnt_b; i += 512) {
        const int r = raw[i];
        const int dl = r & (BNODES - 1);
        const int s = (r >> BSHIFT) & 0xFFFF;
        float ev = a_src[s] + ads[dl];
        ev = ev > 0.f ? ev : NEG * ev;
        const float ex = __expf(ev);
        const int pos = atomicAdd(&cur[dl], 1);
        srtex[pos] = (unsigned)s |
                     ((unsigned)__half_as_ushort(__float2half(ex)) << 16);
    }
    __syncthreads();

    // ---------------- phase 4: node-per-lane-group aggregation -------------
    // 512 threads = 64 groups of 8 lanes; 2 passes over the 128 nodes.
    // Inner body identical to the 113.1-anchor structure.
    {
        const int g  = tid >> 3;        // node slot within pass: 0..63
        const int cq = tid & 7;         // 16B column oct
#pragma unroll
        for (int k = 0; k < 2; ++k) {
            const int ln = k * 64 + g;
            const int node = node0 + ln;
            if (node < NN) {
                const int deg = hist[ln];
                const int rbase = scanb[ln] - deg;

                // self logit from LDS
                float v2 = ass[ln] + ads[ln];
                v2 = v2 > 0.f ? v2 : NEG * v2;
                const float exs = __expf(v2);

                // self row (8 consecutive nodes per wave -> 1KB coalesced)
                uint4 hp = *(const uint4*)(h2 + ((size_t)node << 6) + (cq << 3));

                // 2-deep rolling prefetch over the node's full edge list
                float eA = 0.f, eB = 0.f;
                uint4 gA = make_uint4(0, 0, 0, 0), gB = make_uint4(0, 0, 0, 0);
                if (0 < deg) {
                    const unsigned p = srtex[rbase];      // 8-lane broadcast
                    const int s = (int)(p & 0xffffu);
                    eA = __half2float(__ushort_as_half((unsigned short)(p >> 16)));
                    gA = *(const uint4*)(h2 + ((size_t)s << 6) + (cq << 3));
                }
                if (1 < deg) {
                    const unsigned p = srtex[rbase + 1];
                    const int s = (int)(p & 0xffffu);
                    eB = __half2float(__ushort_as_half((unsigned short)(p >> 16)));
                    gB = *(const uint4*)(h2 + ((size_t)s << 6) + (cq << 3));
                }

                float acc[8];
                {
                    const __half2* hh = (const __half2*)&hp;
#pragma unroll
                    for (int j = 0; j < 4; ++j) {
                        float2 f = __half22float2(hh[j]);
                        acc[2 * j]     = exs * f.x;
                        acc[2 * j + 1] = exs * f.y;
                    }
                }
                float den = exs;   // identical in all 8 lanes of the group

                for (int i = 0; i < deg; ++i) {
                    float eC = 0.f; uint4 gC = make_uint4(0, 0, 0, 0);
                    if (i + 2 < deg) {
                        const unsigned p = srtex[rbase + i + 2];
                        const int s = (int)(p & 0xffffu);
                        eC = __half2float(__ushort_as_half((unsigned short)(p >> 16)));
                        gC = *(const uint4*)(h2 + ((size_t)s << 6) + (cq << 3));
                    }
                    {
                        const __half2* gh = (const __half2*)&gA;
#pragma unroll
                        for (int j = 0; j < 4; ++j) {
                            float2 f = __half22float2(gh[j]);
                            acc[2 * j]     += eA * f.x;
                            acc[2 * j + 1] += eA * f.y;
                        }
                        den += eA;
                    }
                    eA = eB; gA = gB;
                    eB = eC; gB = gC;
                }

                const float inv = 1.f / den;
                const float4 b0 = *(const float4*)(bias + (cq << 3));
                const float4 b1 = *(const float4*)(bias + (cq << 3) + 4);
                float4 o0, o1;
                o0.x = acc[0] * inv + b0.x; o0.y = acc[1] * inv + b0.y;
                o0.z = acc[2] * inv + b0.z; o0.w = acc[3] * inv + b0.w;
                o1.x = acc[4] * inv + b1.x; o1.y = acc[5] * inv + b1.y;
                o1.z = acc[6] * inv + b1.z; o1.w = acc[7] * inv + b1.w;
                float* op = out + ((size_t)node << 6) + (cq << 3);
                *(float4*)op = o0;
                *(float4*)(op + 4) = o1;
            }
        }
    }
}

extern "C" void kernel_launch(void* const* d_in, const int* in_sizes, int n_in,
                              void* d_out, int out_size, void* d_ws, size_t ws_size,
                              hipStream_t stream) {
    const float* x       = (const float*)d_in[0];
    const int*   eidx    = (const int*)d_in[1];   // [2, NE] row-major
    const float* W       = (const float*)d_in[2];
    const float* att_src = (const float*)d_in[3];
    const float* att_dst = (const float*)d_in[4];
    const float* bias    = (const float*)d_in[5];
    float* out = (float*)d_out;

    // ws: h2 [NN*64 fp16 = 6.4MB] | gbucket [391*2560*4 = 4.0MB]
    //   | a_src [NN] | a_dst [NN] | bucket_cur [NBUCK]
    unsigned short* h2 = (unsigned short*)d_ws;
    int*   gbucket = (int*)((char*)d_ws + (size_t)NN * OUT_DIM * 2);
    float* a_src   = (float*)(gbucket + (size_t)NBUCK * HALFCAP);
    float* a_dst   = a_src + NN;
    int*   bucket_cur = (int*)(a_dst + NN);

    const int* src = eidx;
    const int* dst = eidx + NE;

    gat_zero<<<1, 512, 0, stream>>>(bucket_cur);
    gat_gemm_bin<<<GEMM_BLOCKS + BIN_BLOCKS, 512, 0, stream>>>(
        x, W, att_src, att_dst, src, dst, h2, a_src, a_dst, gbucket, bucket_cur);
    gat_sortagg<<<NBUCK, 512, 0, stream>>>(
        gbucket, bucket_cur, (const __half*)h2, a_src, a_dst, bias, out);
}

// Round 14
// 115.212 us; speedup vs baseline: 1.0142x; 1.0018x over previous
//
#include <hip/hip_runtime.h>
#include <hip/hip_fp16.h>

#define NN 50000
#define NE 800000
#define IN_DIM 128
#define OUT_DIM 64
#define NEG 0.2f

#define BSHIFT 7
#define BNODES 128              // nodes per bucket
#define NBUCK 391               // ceil(50000 / 128)
#define HALFCAP 2560            // window per bucket: mean 2048, +11 sigma
#define CHUNK 4096              // edges per bin block
#define BIN_BLOCKS 196          // ceil(NE / CHUNK)
#define GEMM_BLOCKS 391         // ceil(NN / 128)

#define XS_STRIDE 136           // bf16 elems/row: 272 B, 16B-aligned

typedef short short8 __attribute__((ext_vector_type(8)));
typedef float f32x4 __attribute__((ext_vector_type(4)));

__device__ __forceinline__ unsigned short f2bf(float f) {
    unsigned u = __float_as_uint(f);
    u += 0x7FFFu + ((u >> 16) & 1u);
    return (unsigned short)(u >> 16);
}

// ---- Kernel 0: zero the bucket cursors (pure-kernel graph) -----------------
// Experiment ledger (do not retry):
//  - hipMemsetAsync instead of this kernel: +4us (r6/r7)
__global__ __launch_bounds__(512) void gat_zero(int* __restrict__ bucket_cur) {
    if (threadIdx.x < NBUCK) bucket_cur[threadIdx.x] = 0;
}

// ---- Kernel A (512 threads): fused [edge bin-sort] (blocks 0..195, first)
//      and [h2 = fp16(x@W) via bf16 MFMA, 128-row tiles] --------------------
__global__ __launch_bounds__(512) void gat_gemm_bin(
    const float* __restrict__ x, const float* __restrict__ W,
    const float* __restrict__ att_src, const float* __restrict__ att_dst,
    const int* __restrict__ src, const int* __restrict__ dst,
    unsigned short* __restrict__ h2, float* __restrict__ a_src,
    float* __restrict__ a_dst,
    int* __restrict__ gbucket, int* __restrict__ bucket_cur)
{
    __shared__ __align__(16) unsigned short xs[128 * XS_STRIDE]; // 34816 B
    __shared__ __align__(16) unsigned short wt[64 * XS_STRIDE];  // 17408 B
    const int tid = threadIdx.x;
    const int lane = tid & 63, wid = tid >> 6;

    if (blockIdx.x < BIN_BLOCKS) {
        // ---------------- bin sort, single global pass ----------------
        // record = {bkt:9 | src:16 | dlow:7}
        int* recs_in  = (int*)xs;            // [CHUNK] 16 KB
        int* bcnt     = recs_in + CHUNK;     // [512]
        int* cur      = bcnt + 512;          // [512]
        int* lbase    = cur + 512;           // [512]
        int* comb     = lbase + 512;         // [512]
        int* wsum     = comb + 512;          // [8]
        int* recs_out = (int*)wt;            // [CHUNK] 16 KB
        const int e0 = blockIdx.x * CHUNK;
        const int total = (e0 + CHUNK < NE ? CHUNK : NE - e0);

        bcnt[tid] = 0;
        __syncthreads();
#pragma unroll
        for (int k = 0; k < CHUNK / 512; ++k) {
            const int e = e0 + k * 512 + tid;
            if (e < NE) {
                const int d = dst[e];
                const int bkt = d >> BSHIFT;
                recs_in[k * 512 + tid] =
                    (bkt << 23) | (src[e] << BSHIFT) | (d & (BNODES - 1));
                atomicAdd(&bcnt[bkt], 1);
            }
        }
        __syncthreads();
        // wave-shuffle scan of bcnt (512 entries, 8 waves, 2 barriers)
        const int v = bcnt[tid];
        int incl = v;
#pragma unroll
        for (int off = 1; off < 64; off <<= 1) {
            const int n = __shfl_up(incl, off, 64);
            if (lane >= off) incl += n;
        }
        if (lane == 63) wsum[wid] = incl;
        __syncthreads();
        int wpre = 0;
#pragma unroll
        for (int w = 0; w < 8; ++w)
            if (w < wid) wpre += wsum[w];
        const int excl = wpre + incl - v;
        lbase[tid] = excl; cur[tid] = excl;
        int gb = 0;
        if (tid < NBUCK && v) gb = atomicAdd(&bucket_cur[tid], v);
        comb[tid] = gb - excl;
        __syncthreads();
        // place (LDS -> LDS, grouped by bucket)
#pragma unroll
        for (int k = 0; k < CHUNK / 512; ++k) {
            const int idx = k * 512 + tid;
            if (idx < total) {
                const int r = recs_in[idx];
                const unsigned bkt = (unsigned)r >> 23;
                const int pos = atomicAdd(&cur[bkt], 1);
                recs_out[pos] = r;
            }
        }
        __syncthreads();
        // coalesced flush
        for (int j = tid; j < total; j += 512) {
            const int r = recs_out[j];
            const unsigned bkt = (unsigned)r >> 23;
            const int rel = comb[bkt] + j;
            if (rel < HALFCAP)
                gbucket[bkt * HALFCAP + rel] = r & 0x7FFFFF;
        }
        return;
    }

    // ---------------- GEMM path: bf16 MFMA, 128x64 tile, 8 waves -------
    const int block_row = (blockIdx.x - BIN_BLOCKS) * 128;

    for (int t = tid; t < 128 * 32; t += 512) {
        const int r = t >> 5, k = (t & 31) << 2;
        const int row = block_row + r;
        float4 v = make_float4(0.f, 0.f, 0.f, 0.f);
        if (row < NN) v = *(const float4*)(x + (size_t)row * IN_DIM + k);
        ushort4 p;
        p.x = f2bf(v.x); p.y = f2bf(v.y); p.z = f2bf(v.z); p.w = f2bf(v.w);
        *(ushort4*)&xs[r * XS_STRIDE + k] = p;
    }
    for (int t = tid; t < 128 * 16; t += 512) {
        const int k = t >> 4, n4 = (t & 15) << 2;
        const float4 v = *(const float4*)(W + k * 64 + n4);
        wt[(n4 + 0) * XS_STRIDE + k] = f2bf(v.x);
        wt[(n4 + 1) * XS_STRIDE + k] = f2bf(v.y);
        wt[(n4 + 2) * XS_STRIDE + k] = f2bf(v.z);
        wt[(n4 + 3) * XS_STRIDE + k] = f2bf(v.w);
    }
    __syncthreads();

    const int m = lane & 15, quad = lane >> 4;

    f32x4 acc[4];
#pragma unroll
    for (int ct = 0; ct < 4; ++ct) acc[ct] = (f32x4){0.f, 0.f, 0.f, 0.f};

    const unsigned short* xrow = &xs[(wid * 16 + m) * XS_STRIDE + quad * 8];
#pragma unroll
    for (int kt = 0; kt < 4; ++kt) {
        short8 af = *(const short8*)(xrow + kt * 32);
#pragma unroll
        for (int ct = 0; ct < 4; ++ct) {
            short8 bf = *(const short8*)(&wt[(ct * 16 + m) * XS_STRIDE + kt * 32 + quad * 8]);
            acc[ct] = __builtin_amdgcn_mfma_f32_16x16x32_bf16(af, bf, acc[ct], 0, 0, 0);
        }
    }

    float as_c[4], ad_c[4];
#pragma unroll
    for (int ct = 0; ct < 4; ++ct) {
        as_c[ct] = att_src[ct * 16 + m];
        ad_c[ct] = att_dst[ct * 16 + m];
    }
    float ps[4], pd[4];
#pragma unroll
    for (int reg = 0; reg < 4; ++reg) {
        float s = 0.f, d = 0.f;
#pragma unroll
        for (int ct = 0; ct < 4; ++ct) {
            s += acc[ct][reg] * as_c[ct];
            d += acc[ct][reg] * ad_c[ct];
        }
        ps[reg] = s; pd[reg] = d;
    }
#pragma unroll
    for (int off = 1; off < 16; off <<= 1) {
#pragma unroll
        for (int reg = 0; reg < 4; ++reg) {
            ps[reg] += __shfl_xor(ps[reg], off, 64);
            pd[reg] += __shfl_xor(pd[reg], off, 64);
        }
    }
    if (m == 0) {
#pragma unroll
        for (int reg = 0; reg < 4; ++reg) {
            const int row = block_row + wid * 16 + quad * 4 + reg;
            if (row < NN) { a_src[row] = ps[reg]; a_dst[row] = pd[reg]; }
        }
    }

    __syncthreads();
    unsigned short* hs = xs;               // 128 rows x stride 72
#pragma unroll
    for (int ct = 0; ct < 4; ++ct)
#pragma unroll
        for (int reg = 0; reg < 4; ++reg)
            hs[(wid * 16 + quad * 4 + reg) * 72 + ct * 16 + m] =
                __half_as_ushort(__float2half(acc[ct][reg]));
    __syncthreads();
    {
        const int r = tid >> 2, c = (tid & 3) * 16;
        const int row = block_row + r;
        if (row < NN) {
            uint4 v0 = *(const uint4*)&hs[r * 72 + c];
            uint4 v1 = *(const uint4*)&hs[r * 72 + c + 8];
            *(uint4*)(h2 + (size_t)row * 64 + c) = v0;
            *(uint4*)(h2 + (size_t)row * 64 + c + 8) = v1;
        }
    }
}

// ---- Kernel B: FUSED per-bucket counting sort (LDS) + exp + aggregation ----
// 391 blocks (one per 128-node bucket), 1024 threads. R4 anchor = 113.1us.
// Experiment ledger on this kernel (do not retry):
//  - reg-resident pass-1 (no raw[]):      ~neutral   (r6/r7)
//  - 4-deep gather pipeline:              +3.3us     (r9, VGPR cliff)
//  - __launch_bounds__(1024,8) VGPR cap:  +2.4us     (r11, spills)
//  - 16-lane/node, 4-col, 2-pass:         +3.7us     (r12)
//  - 512-thread blocks, 2-pass phase 4:   +2.3us     (r13, phases 1-3 amplify)
__global__ __launch_bounds__(1024) void gat_sortagg(
    const int* __restrict__ gbucket, const int* __restrict__ bucket_cur,
    const __half* __restrict__ h2, const float* __restrict__ a_src,
    const float* __restrict__ a_dst, const float* __restrict__ bias,
    float* __restrict__ out)
{
    __shared__ int raw[HALFCAP];                 // 10.2 KB
    __shared__ unsigned srtex[HALFCAP];          // 10.2 KB packed {ex, src}
    __shared__ int hist[BNODES];
    __shared__ int scanb[BNODES];
    __shared__ int cur[BNODES];
    __shared__ float ads[BNODES];
    __shared__ float ass[BNODES];                // own-node a_src cache
    __shared__ int wsum[2];
    const int b = blockIdx.x;
    const int tid = threadIdx.x;
    const int node0 = b << BSHIFT;

    int cnt_b = bucket_cur[b];
    if (cnt_b > HALFCAP) cnt_b = HALFCAP;
    const int* win = gbucket + (size_t)b * HALFCAP;

    if (tid < BNODES) {
        hist[tid] = 0;
        const int n = node0 + tid;
        ads[tid] = (n < NN) ? a_dst[n] : 0.f;
        ass[tid] = (n < NN) ? a_src[n] : 0.f;
    }
    __syncthreads();
    for (int i = tid; i < cnt_b; i += 1024) {
        const int r = win[i];
        raw[i] = r;
        atomicAdd(&hist[r & (BNODES - 1)], 1);
    }
    __syncthreads();
    // wave-shuffle scan of hist (128 entries, 2 waves, 2 barriers)
    const int lane = tid & 63;
    int v = 0, incl = 0;
    if (tid < BNODES) {
        v = hist[tid];
        incl = v;
#pragma unroll
        for (int off = 1; off < 64; off <<= 1) {
            const int n = __shfl_up(incl, off, 64);
            if (lane >= off) incl += n;
        }
        if (lane == 63) wsum[tid >> 6] = incl;
    }
    __syncthreads();
    if (tid < BNODES) {
        const int inclT = incl + ((tid >= 64) ? wsum[0] : 0);
        scanb[tid] = inclT;
        cur[tid] = inclT - v;
    }
    __syncthreads();
    for (int i = tid; i < cnt_b; i += 1024) {
        const int r = raw[i];
        const int dl = r & (BNODES - 1);
        const int s = (r >> BSHIFT) & 0xFFFF;
        float ev = a_src[s] + ads[dl];
        ev = ev > 0.f ? ev : NEG * ev;
        const float ex = __expf(ev);
        const int pos = atomicAdd(&cur[dl], 1);
        srtex[pos] = (unsigned)s |
                     ((unsigned)__half_as_ushort(__float2half(ex)) << 16);
    }
    __syncthreads();

    // ---------------- phase 4: node-per-lane-group aggregation -------------
    // 1024 threads = 128 groups of 8 lanes; group g owns node node0+g,
    // lane (tid&7) owns columns [8*(tid&7) .. 8*(tid&7)+7].
    {
        const int g  = tid >> 3;        // node slot 0..127
        const int cq = tid & 7;         // 16B column oct
        const int node = node0 + g;
        if (node < NN) {
            const int deg = hist[g];
            const int rbase = scanb[g] - deg;

            // self logit from LDS
            float v2 = ass[g] + ads[g];
            v2 = v2 > 0.f ? v2 : NEG * v2;
            const float exs = __expf(v2);

            // self row (8 consecutive nodes per wave -> 1KB coalesced)
            uint4 hp = *(const uint4*)(h2 + ((size_t)node << 6) + (cq << 3));

            // 2-deep rolling prefetch over the node's full edge list
            float eA = 0.f, eB = 0.f;
            uint4 gA = make_uint4(0, 0, 0, 0), gB = make_uint4(0, 0, 0, 0);
            if (0 < deg) {
                const unsigned p = srtex[rbase];          // 8-lane broadcast
                const int s = (int)(p & 0xffffu);
                eA = __half2float(__ushort_as_half((unsigned short)(p >> 16)));
                gA = *(const uint4*)(h2 + ((size_t)s << 6) + (cq << 3));
            }
            if (1 < deg) {
                const unsigned p = srtex[rbase + 1];
                const int s = (int)(p & 0xffffu);
                eB = __half2float(__ushort_as_half((unsigned short)(p >> 16)));
                gB = *(const uint4*)(h2 + ((size_t)s << 6) + (cq << 3));
            }

            float acc[8];
            {
                const __half2* hh = (const __half2*)&hp;
#pragma unroll
                for (int j = 0; j < 4; ++j) {
                    float2 f = __half22float2(hh[j]);
                    acc[2 * j]     = exs * f.x;
                    acc[2 * j + 1] = exs * f.y;
                }
            }
            float den = exs;   // identical in all 8 lanes of the group

            for (int i = 0; i < deg; ++i) {
                float eC = 0.f; uint4 gC = make_uint4(0, 0, 0, 0);
                if (i + 2 < deg) {
                    const unsigned p = srtex[rbase + i + 2];
                    const int s = (int)(p & 0xffffu);
                    eC = __half2float(__ushort_as_half((unsigned short)(p >> 16)));
                    gC = *(const uint4*)(h2 + ((size_t)s << 6) + (cq << 3));
                }
                {
                    const __half2* gh = (const __half2*)&gA;
#pragma unroll
                    for (int j = 0; j < 4; ++j) {
                        float2 f = __half22float2(gh[j]);
                        acc[2 * j]     += eA * f.x;
                        acc[2 * j + 1] += eA * f.y;
                    }
                    den += eA;
                }
                eA = eB; gA = gB;
                eB = eC; gB = gC;
            }

#pragma unroll
            for (int j = 0; j < 0; ++j) {}  // (structure marker, no-op)

            const float inv = 1.f / den;
            const float4 b0 = *(const float4*)(bias + (cq << 3));
            const float4 b1 = *(const float4*)(bias + (cq << 3) + 4);
            float4 o0, o1;
            o0.x = acc[0] * inv + b0.x; o0.y = acc[1] * inv + b0.y;
            o0.z = acc[2] * inv + b0.z; o0.w = acc[3] * inv + b0.w;
            o1.x = acc[4] * inv + b1.x; o1.y = acc[5] * inv + b1.y;
            o1.z = acc[6] * inv + b1.z; o1.w = acc[7] * inv + b1.w;
            // wave writes 8 consecutive nodes x 256B = 2KB contiguous
            float* op = out + ((size_t)node << 6) + (cq << 3);
            *(float4*)op = o0;
            *(float4*)(op + 4) = o1;
        }
    }
}

extern "C" void kernel_launch(void* const* d_in, const int* in_sizes, int n_in,
                              void* d_out, int out_size, void* d_ws, size_t ws_size,
                              hipStream_t stream) {
    const float* x       = (const float*)d_in[0];
    const int*   eidx    = (const int*)d_in[1];   // [2, NE] row-major
    const float* W       = (const float*)d_in[2];
    const float* att_src = (const float*)d_in[3];
    const float* att_dst = (const float*)d_in[4];
    const float* bias    = (const float*)d_in[5];
    float* out = (float*)d_out;

    // ws: h2 [NN*64 fp16 = 6.4MB] | gbucket [391*2560*4 = 4.0MB]
    //   | a_src [NN] | a_dst [NN] | bucket_cur [NBUCK]
    unsigned short* h2 = (unsigned short*)d_ws;
    int*   gbucket = (int*)((char*)d_ws + (size_t)NN * OUT_DIM * 2);
    float* a_src   = (float*)(gbucket + (size_t)NBUCK * HALFCAP);
    float* a_dst   = a_src + NN;
    int*   bucket_cur = (int*)(a_dst + NN);

    const int* src = eidx;
    const int* dst = eidx + NE;

    gat_zero<<<1, 512, 0, stream>>>(bucket_cur);
    gat_gemm_bin<<<GEMM_BLOCKS + BIN_BLOCKS, 512, 0, stream>>>(
        x, W, att_src, att_dst, src, dst, h2, a_src, a_dst, gbucket, bucket_cur);
    gat_sortagg<<<NBUCK, 1024, 0, stream>>>(
        gbucket, bucket_cur, (const __half*)h2, a_src, a_dst, bias, out);
}

// Round 15
// 113.742 us; speedup vs baseline: 1.0273x; 1.0129x over previous
//
#include <hip/hip_runtime.h>
#include <hip/hip_fp16.h>

#define NN 50000
#define NE 800000
#define IN_DIM 128
#define OUT_DIM 64
#define NEG 0.2f

#define BSHIFT 7
#define BNODES 128              // nodes per bucket
#define NBUCK 391               // ceil(50000 / 128)
#define HALFCAP 2560            // window per bucket: mean 2048, +11 sigma
#define CHUNK 4096              // edges per bin block
#define BIN_BLOCKS 196          // ceil(NE / CHUNK)
#define GEMM_BLOCKS 391         // ceil(NN / 128)

#define XS_STRIDE 136           // bf16 elems/row: 272 B, 16B-aligned

typedef short short8 __attribute__((ext_vector_type(8)));
typedef float f32x4 __attribute__((ext_vector_type(4)));

__device__ __forceinline__ unsigned short f2bf(float f) {
    unsigned u = __float_as_uint(f);
    u += 0x7FFFu + ((u >> 16) & 1u);
    return (unsigned short)(u >> 16);
}

// ---- Kernel 0: zero cursors + pre-transpose W to bf16 (17 blocks) ----------
// Replaces gat_zero (1 block, 255 CUs idle). Block 0: cursors. Blocks 1..16:
// wsWT[n][k] = bf16(W[k][n]) once, instead of per-GEMM-block (391x) fp32
// read + convert + LDS scatter. Ledger: hipMemsetAsync for cursors: +4us
// (r6/r7) -- keep kernel-based zeroing.
__global__ __launch_bounds__(512) void gat_prep(
    const float* __restrict__ W, unsigned short* __restrict__ wsWT,
    int* __restrict__ bucket_cur)
{
    if (blockIdx.x == 0) {
        if (threadIdx.x < NBUCK) bucket_cur[threadIdx.x] = 0;
    } else {
        const int o = (blockIdx.x - 1) * 512 + threadIdx.x;  // 0..8191
        const int k = o >> 6, n = o & 63;   // consecutive tid -> consecutive n
        wsWT[n * 128 + k] = f2bf(W[k * 64 + n]);             // coalesced read
    }
}

// ---- Kernel A (512 threads): fused [edge bin-sort] (blocks 0..195, first)
//      and [h2 = fp16(x@W) via bf16 MFMA, 128-row tiles] --------------------
__global__ __launch_bounds__(512) void gat_gemm_bin(
    const float* __restrict__ x, const unsigned short* __restrict__ wsWT,
    const float* __restrict__ att_src, const float* __restrict__ att_dst,
    const int* __restrict__ src, const int* __restrict__ dst,
    unsigned short* __restrict__ h2, float* __restrict__ a_src,
    float* __restrict__ a_dst,
    int* __restrict__ gbucket, int* __restrict__ bucket_cur)
{
    __shared__ __align__(16) unsigned short xs[128 * XS_STRIDE]; // 34816 B
    __shared__ __align__(16) unsigned short wt[64 * XS_STRIDE];  // 17408 B
    const int tid = threadIdx.x;
    const int lane = tid & 63, wid = tid >> 6;

    if (blockIdx.x < BIN_BLOCKS) {
        // ---------------- bin sort, single global pass ----------------
        // record = {bkt:9 | src:16 | dlow:7}
        int* recs_in  = (int*)xs;            // [CHUNK] 16 KB
        int* bcnt     = recs_in + CHUNK;     // [512]
        int* cur      = bcnt + 512;          // [512]
        int* lbase    = cur + 512;           // [512]
        int* comb     = lbase + 512;         // [512]
        int* wsum     = comb + 512;          // [8]
        int* recs_out = (int*)wt;            // [CHUNK] 16 KB
        const int e0 = blockIdx.x * CHUNK;
        const int total = (e0 + CHUNK < NE ? CHUNK : NE - e0);

        bcnt[tid] = 0;
        __syncthreads();
#pragma unroll
        for (int k = 0; k < CHUNK / 512; ++k) {
            const int e = e0 + k * 512 + tid;
            if (e < NE) {
                const int d = dst[e];
                const int bkt = d >> BSHIFT;
                recs_in[k * 512 + tid] =
                    (bkt << 23) | (src[e] << BSHIFT) | (d & (BNODES - 1));
                atomicAdd(&bcnt[bkt], 1);
            }
        }
        __syncthreads();
        // wave-shuffle scan of bcnt (512 entries, 8 waves, 2 barriers)
        const int v = bcnt[tid];
        int incl = v;
#pragma unroll
        for (int off = 1; off < 64; off <<= 1) {
            const int n = __shfl_up(incl, off, 64);
            if (lane >= off) incl += n;
        }
        if (lane == 63) wsum[wid] = incl;
        __syncthreads();
        int wpre = 0;
#pragma unroll
        for (int w = 0; w < 8; ++w)
            if (w < wid) wpre += wsum[w];
        const int excl = wpre + incl - v;
        lbase[tid] = excl; cur[tid] = excl;
        int gb = 0;
        if (tid < NBUCK && v) gb = atomicAdd(&bucket_cur[tid], v);
        comb[tid] = gb - excl;
        __syncthreads();
        // place (LDS -> LDS, grouped by bucket)
#pragma unroll
        for (int k = 0; k < CHUNK / 512; ++k) {
            const int idx = k * 512 + tid;
            if (idx < total) {
                const int r = recs_in[idx];
                const unsigned bkt = (unsigned)r >> 23;
                const int pos = atomicAdd(&cur[bkt], 1);
                recs_out[pos] = r;
            }
        }
        __syncthreads();
        // coalesced flush
        for (int j = tid; j < total; j += 512) {
            const int r = recs_out[j];
            const unsigned bkt = (unsigned)r >> 23;
            const int rel = comb[bkt] + j;
            if (rel < HALFCAP)
                gbucket[bkt * HALFCAP + rel] = r & 0x7FFFFF;
        }
        return;
    }

    // ---------------- GEMM path: bf16 MFMA, 128x64 tile, 8 waves -------
    const int block_row = (blockIdx.x - BIN_BLOCKS) * 128;

    for (int t = tid; t < 128 * 32; t += 512) {
        const int r = t >> 5, k = (t & 31) << 2;
        const int row = block_row + r;
        float4 v = make_float4(0.f, 0.f, 0.f, 0.f);
        if (row < NN) v = *(const float4*)(x + (size_t)row * IN_DIM + k);
        ushort4 p;
        p.x = f2bf(v.x); p.y = f2bf(v.y); p.z = f2bf(v.z); p.w = f2bf(v.w);
        *(ushort4*)&xs[r * XS_STRIDE + k] = p;
    }
    // W tile: pre-converted bf16 W^T from workspace, 16B vector copy (2 iters)
    for (int t = tid; t < 64 * 16; t += 512) {
        const int n = t >> 4, k8 = (t & 15) << 3;
        *(short8*)&wt[n * XS_STRIDE + k8] = *(const short8*)(wsWT + n * 128 + k8);
    }
    __syncthreads();

    const int m = lane & 15, quad = lane >> 4;

    f32x4 acc[4];
#pragma unroll
    for (int ct = 0; ct < 4; ++ct) acc[ct] = (f32x4){0.f, 0.f, 0.f, 0.f};

    const unsigned short* xrow = &xs[(wid * 16 + m) * XS_STRIDE + quad * 8];
#pragma unroll
    for (int kt = 0; kt < 4; ++kt) {
        short8 af = *(const short8*)(xrow + kt * 32);
#pragma unroll
        for (int ct = 0; ct < 4; ++ct) {
            short8 bf = *(const short8*)(&wt[(ct * 16 + m) * XS_STRIDE + kt * 32 + quad * 8]);
            acc[ct] = __builtin_amdgcn_mfma_f32_16x16x32_bf16(af, bf, acc[ct], 0, 0, 0);
        }
    }

    float as_c[4], ad_c[4];
#pragma unroll
    for (int ct = 0; ct < 4; ++ct) {
        as_c[ct] = att_src[ct * 16 + m];
        ad_c[ct] = att_dst[ct * 16 + m];
    }
    float ps[4], pd[4];
#pragma unroll
    for (int reg = 0; reg < 4; ++reg) {
        float s = 0.f, d = 0.f;
#pragma unroll
        for (int ct = 0; ct < 4; ++ct) {
            s += acc[ct][reg] * as_c[ct];
            d += acc[ct][reg] * ad_c[ct];
        }
        ps[reg] = s; pd[reg] = d;
    }
#pragma unroll
    for (int off = 1; off < 16; off <<= 1) {
#pragma unroll
        for (int reg = 0; reg < 4; ++reg) {
            ps[reg] += __shfl_xor(ps[reg], off, 64);
            pd[reg] += __shfl_xor(pd[reg], off, 64);
        }
    }
    if (m == 0) {
#pragma unroll
        for (int reg = 0; reg < 4; ++reg) {
            const int row = block_row + wid * 16 + quad * 4 + reg;
            if (row < NN) { a_src[row] = ps[reg]; a_dst[row] = pd[reg]; }
        }
    }

    __syncthreads();
    unsigned short* hs = xs;               // 128 rows x stride 72
#pragma unroll
    for (int ct = 0; ct < 4; ++ct)
#pragma unroll
        for (int reg = 0; reg < 4; ++reg)
            hs[(wid * 16 + quad * 4 + reg) * 72 + ct * 16 + m] =
                __half_as_ushort(__float2half(acc[ct][reg]));
    __syncthreads();
    {
        const int r = tid >> 2, c = (tid & 3) * 16;
        const int row = block_row + r;
        if (row < NN) {
            uint4 v0 = *(const uint4*)&hs[r * 72 + c];
            uint4 v1 = *(const uint4*)&hs[r * 72 + c + 8];
            *(uint4*)(h2 + (size_t)row * 64 + c) = v0;
            *(uint4*)(h2 + (size_t)row * 64 + c + 8) = v1;
        }
    }
}

// ---- Kernel B: FUSED per-bucket counting sort (LDS) + exp + aggregation ----
// 391 blocks (one per 128-node bucket), 1024 threads. Anchor structure
// (113.1 r4; 115.2 r14 re-measure -> run noise ~±2us).
// Experiment ledger on this kernel (all within/near noise, do not retry):
//  - reg-resident pass-1 (no raw[]):      ~neutral   (r6/r7)
//  - 4-deep gather pipeline:              +3.3us     (r9)
//  - __launch_bounds__(1024,8) VGPR cap:  +2.4us     (r11, spills)
//  - 16-lane/node, 4-col, 2-pass:         +3.7us     (r12)
//  - 512-thread blocks, 2-pass phase 4:   +2.3us     (r13)
__global__ __launch_bounds__(1024) void gat_sortagg(
    const int* __restrict__ gbucket, const int* __restrict__ bucket_cur,
    const __half* __restrict__ h2, const float* __restrict__ a_src,
    const float* __restrict__ a_dst, const float* __restrict__ bias,
    float* __restrict__ out)
{
    __shared__ int raw[HALFCAP];                 // 10.2 KB
    __shared__ unsigned srtex[HALFCAP];          // 10.2 KB packed {ex, src}
    __shared__ int hist[BNODES];
    __shared__ int scanb[BNODES];
    __shared__ int cur[BNODES];
    __shared__ float ads[BNODES];
    __shared__ float ass[BNODES];                // own-node a_src cache
    __shared__ int wsum[2];
    const int b = blockIdx.x;
    const int tid = threadIdx.x;
    const int node0 = b << BSHIFT;

    int cnt_b = bucket_cur[b];
    if (cnt_b > HALFCAP) cnt_b = HALFCAP;
    const int* win = gbucket + (size_t)b * HALFCAP;

    if (tid < BNODES) {
        hist[tid] = 0;
        const int n = node0 + tid;
        ads[tid] = (n < NN) ? a_dst[n] : 0.f;
        ass[tid] = (n < NN) ? a_src[n] : 0.f;
    }
    __syncthreads();
    for (int i = tid; i < cnt_b; i += 1024) {
        const int r = win[i];
        raw[i] = r;
        atomicAdd(&hist[r & (BNODES - 1)], 1);
    }
    __syncthreads();
    // wave-shuffle scan of hist (128 entries, 2 waves, 2 barriers)
    const int lane = tid & 63;
    int v = 0, incl = 0;
    if (tid < BNODES) {
        v = hist[tid];
        incl = v;
#pragma unroll
        for (int off = 1; off < 64; off <<= 1) {
            const int n = __shfl_up(incl, off, 64);
            if (lane >= off) incl += n;
        }
        if (lane == 63) wsum[tid >> 6] = incl;
    }
    __syncthreads();
    if (tid < BNODES) {
        const int inclT = incl + ((tid >= 64) ? wsum[0] : 0);
        scanb[tid] = inclT;
        cur[tid] = inclT - v;
    }
    __syncthreads();
    for (int i = tid; i < cnt_b; i += 1024) {
        const int r = raw[i];
        const int dl = r & (BNODES - 1);
        const int s = (r >> BSHIFT) & 0xFFFF;
        float ev = a_src[s] + ads[dl];
        ev = ev > 0.f ? ev : NEG * ev;
        const float ex = __expf(ev);
        const int pos = atomicAdd(&cur[dl], 1);
        srtex[pos] = (unsigned)s |
                     ((unsigned)__half_as_ushort(__float2half(ex)) << 16);
    }
    __syncthreads();

    // ---------------- phase 4: node-per-lane-group aggregation -------------
    // 1024 threads = 128 groups of 8 lanes; group g owns node node0+g,
    // lane (tid&7) owns columns [8*(tid&7) .. 8*(tid&7)+7].
    {
        const int g  = tid >> 3;        // node slot 0..127
        const int cq = tid & 7;         // 16B column oct
        const int node = node0 + g;
        if (node < NN) {
            const int deg = hist[g];
            const int rbase = scanb[g] - deg;

            // self logit from LDS
            float v2 = ass[g] + ads[g];
            v2 = v2 > 0.f ? v2 : NEG * v2;
            const float exs = __expf(v2);

            // self row (8 consecutive nodes per wave -> 1KB coalesced)
            uint4 hp = *(const uint4*)(h2 + ((size_t)node << 6) + (cq << 3));

            // 2-deep rolling prefetch over the node's full edge list
            float eA = 0.f, eB = 0.f;
            uint4 gA = make_uint4(0, 0, 0, 0), gB = make_uint4(0, 0, 0, 0);
            if (0 < deg) {
                const unsigned p = srtex[rbase];          // 8-lane broadcast
                const int s = (int)(p & 0xffffu);
                eA = __half2float(__ushort_as_half((unsigned short)(p >> 16)));
                gA = *(const uint4*)(h2 + ((size_t)s << 6) + (cq << 3));
            }
            if (1 < deg) {
                const unsigned p = srtex[rbase + 1];
                const int s = (int)(p & 0xffffu);
                eB = __half2float(__ushort_as_half((unsigned short)(p >> 16)));
                gB = *(const uint4*)(h2 + ((size_t)s << 6) + (cq << 3));
            }

            float acc[8];
            {
                const __half2* hh = (const __half2*)&hp;
#pragma unroll
                for (int j = 0; j < 4; ++j) {
                    float2 f = __half22float2(hh[j]);
                    acc[2 * j]     = exs * f.x;
                    acc[2 * j + 1] = exs * f.y;
                }
            }
            float den = exs;   // identical in all 8 lanes of the group

            for (int i = 0; i < deg; ++i) {
                float eC = 0.f; uint4 gC = make_uint4(0, 0, 0, 0);
                if (i + 2 < deg) {
                    const unsigned p = srtex[rbase + i + 2];
                    const int s = (int)(p & 0xffffu);
                    eC = __half2float(__ushort_as_half((unsigned short)(p >> 16)));
                    gC = *(const uint4*)(h2 + ((size_t)s << 6) + (cq << 3));
                }
                {
                    const __half2* gh = (const __half2*)&gA;
#pragma unroll
                    for (int j = 0; j < 4; ++j) {
                        float2 f = __half22float2(gh[j]);
                        acc[2 * j]     += eA * f.x;
                        acc[2 * j + 1] += eA * f.y;
                    }
                    den += eA;
                }
                eA = eB; gA = gB;
                eB = eC; gB = gC;
            }

            const float inv = 1.f / den;
            const float4 b0 = *(const float4*)(bias + (cq << 3));
            const float4 b1 = *(const float4*)(bias + (cq << 3) + 4);
            float4 o0, o1;
            o0.x = acc[0] * inv + b0.x; o0.y = acc[1] * inv + b0.y;
            o0.z = acc[2] * inv + b0.z; o0.w = acc[3] * inv + b0.w;
            o1.x = acc[4] * inv + b1.x; o1.y = acc[5] * inv + b1.y;
            o1.z = acc[6] * inv + b1.z; o1.w = acc[7] * inv + b1.w;
            // wave writes 8 consecutive nodes x 256B = 2KB contiguous
            float* op = out + ((size_t)node << 6) + (cq << 3);
            *(float4*)op = o0;
            *(float4*)(op + 4) = o1;
        }
    }
}

extern "C" void kernel_launch(void* const* d_in, const int* in_sizes, int n_in,
                              void* d_out, int out_size, void* d_ws, size_t ws_size,
                              hipStream_t stream) {
    const float* x       = (const float*)d_in[0];
    const int*   eidx    = (const int*)d_in[1];   // [2, NE] row-major
    const float* W       = (const float*)d_in[2];
    const float* att_src = (const float*)d_in[3];
    const float* att_dst = (const float*)d_in[4];
    const float* bias    = (const float*)d_in[5];
    float* out = (float*)d_out;

    // ws: h2 [NN*64 fp16 = 6.4MB] | gbucket [391*2560*4 = 4.0MB]
    //   | wsWT [64*128 bf16 = 16KB, 16B-aligned] | a_src | a_dst | bucket_cur
    unsigned short* h2 = (unsigned short*)d_ws;
    int*   gbucket = (int*)((char*)d_ws + (size_t)NN * OUT_DIM * 2);
    unsigned short* wsWT = (unsigned short*)(gbucket + (size_t)NBUCK * HALFCAP);
    float* a_src   = (float*)(wsWT + 64 * 128);
    float* a_dst   = a_src + NN;
    int*   bucket_cur = (int*)(a_dst + NN);

    const int* src = eidx;
    const int* dst = eidx + NE;

    gat_prep<<<17, 512, 0, stream>>>(W, wsWT, bucket_cur);
    gat_gemm_bin<<<GEMM_BLOCKS + BIN_BLOCKS, 512, 0, stream>>>(
        x, wsWT, att_src, att_dst, src, dst, h2, a_src, a_dst, gbucket, bucket_cur);
    gat_sortagg<<<NBUCK, 1024, 0, stream>>>(
        gbucket, bucket_cur, (const __half*)h2, a_src, a_dst, bias, out);
}